// Round 14
// baseline (437.993 us; speedup 1.0000x reference)
//
#include <hip/hip_runtime.h>
#include <hip/hip_bf16.h>
#include <stdint.h>

// KAN layer = one augmented GEMM:
//   out[4096,1024] = [silu(x) | rbf_basis(x)] @ [W_base ; W_spline]
// R10 -> R11: GEMM restructure. R10 PMC: conflicts 0, MfmaUtil 32%, HBM 28%,
// VALU 15% -> nothing saturated => 2-barrier stage-drain stall (m233).
// New gemm256: 256x256x64 tile, 8 waves (2Mx4N, 128x64 each), 2 LDS buffers
// (128 KB), counted-vmcnt pipeline:
//   iter t: vmcnt(8)[tile t landed]; barrier; ds_read 24 frags(buf c=t&1);
//           lgkmcnt(0); barrier [buf c dead]; stage tile t+2 -> buf c (8 loads);
//           setprio(1); 64 MFMA; setprio(0)
// 16 loads in flight steady-state, vmcnt never 0 until last iter (T3/T4).
// Verified R10 parts carried: chunk-XOR involution swizzle, frag formulas,
// atomic epilogue, XCD swizzle, prep kernels, npass ws ladder.

typedef short short8 __attribute__((ext_vector_type(8)));
typedef __bf16 bf16x8 __attribute__((ext_vector_type(8)));
typedef float f32x4 __attribute__((ext_vector_type(4)));
typedef unsigned int u32;

#define VMCNT8() asm volatile("s_waitcnt vmcnt(8)" ::: "memory")
#define VMCNT0() asm volatile("s_waitcnt vmcnt(0)" ::: "memory")
#define LGKM0()  asm volatile("s_waitcnt lgkmcnt(0)" ::: "memory")

__device__ __forceinline__ unsigned short f2bf(float f) {
  __hip_bfloat16 h = __float2bfloat16(f);
  return __builtin_bit_cast(unsigned short, h);
}

__device__ __forceinline__ void gload_lds16(const unsigned short* g, unsigned short* l) {
  // async global->LDS, 16B per lane; LDS dest = wave-uniform base (+lane*16 by HW)
  __builtin_amdgcn_global_load_lds(
      (const __attribute__((address_space(1))) u32*)(const void*)g,
      (__attribute__((address_space(3))) u32*)(void*)l, 16, 0, 0);
}

// ---------------- prep kernels (unchanged, verified) ----------------

__global__ void prep_silu(const float* __restrict__ x, unsigned short* __restrict__ A, int ld) {
  int g = blockIdx.x * 256 + threadIdx.x;
  int row = g >> 7;
  int col = (g & 127) * 8;
  const float4* x4 = reinterpret_cast<const float4*>(x);
  float4 a = x4[g * 2], b = x4[g * 2 + 1];
  float v[8] = {a.x, a.y, a.z, a.w, b.x, b.y, b.z, b.w};
  union { unsigned short u[8]; short8 v8; } o;
#pragma unroll
  for (int j = 0; j < 8; ++j) {
    float s = v[j] / (1.f + __expf(-v[j]));
    o.u[j] = f2bf(s);
  }
  *reinterpret_cast<short8*>(&A[(size_t)row * ld + col]) = o.v8;
}

__global__ void prep_basis(const float* __restrict__ x, unsigned short* __restrict__ A,
                           int i0, int L, int ld, int col_off) {
  int g = blockIdx.x * 256 + threadIdx.x;
  int e0 = g * 8;
  int b = e0 / L;
  int k0 = e0 - b * L;
  const float* xr = x + (size_t)b * 1024 + i0;
  union { unsigned short u[8]; short8 v8; } o;
#pragma unroll
  for (int j = 0; j < 8; ++j) {
    int k = k0 + j;
    int il = (int)(((unsigned)k * 104858u) >> 21);  // k/20, exact for k < 262144
    int gg = k - il * 20;
    float xv = xr[il];
    float d = (xv + 2.0f) * 4.75f - (float)gg;
    o.u[j] = f2bf(__expf(-d * d));
  }
  *reinterpret_cast<short8*>(&A[(size_t)b * ld + col_off + k0]) = o.v8;
}

__global__ void prep_wt(const float* __restrict__ W, unsigned short* __restrict__ Bt,
                        int Kp, int ldbt, int k_off) {
  __shared__ unsigned short tile[64][72];
  int tiles_k = Kp >> 6;
  int bk = blockIdx.x % tiles_k, bn = blockIdx.x / tiles_k;
  int t = threadIdx.x;
  int lr = t >> 4;
  int lc = (t & 15) * 4;
#pragma unroll
  for (int r = 0; r < 4; ++r) {
    int row = r * 16 + lr;
    float4 v = *reinterpret_cast<const float4*>(&W[(size_t)(bk * 64 + row) * 1024 + bn * 64 + lc]);
    tile[row][lc + 0] = f2bf(v.x);
    tile[row][lc + 1] = f2bf(v.y);
    tile[row][lc + 2] = f2bf(v.z);
    tile[row][lc + 3] = f2bf(v.w);
  }
  __syncthreads();
  int nr = t >> 3;
  int kc = (t & 7) * 8;
#pragma unroll
  for (int r = 0; r < 2; ++r) {
    int n = r * 32 + nr;
    union { unsigned short u[8]; short8 v8; } o;
#pragma unroll
    for (int j = 0; j < 8; ++j) o.u[j] = tile[kc + j][n];
    *reinterpret_cast<short8*>(&Bt[(size_t)(bn * 64 + n) * ldbt + k_off + bk * 64 + kc]) = o.v8;
  }
}

// ---------------- GEMM 256x256, counted-vmcnt pipeline ----------------
// C += A @ Bt^T. grid = 4z * 64 tiles (16 M x 4 N); 512 thr = 8 waves (2Mx4N).
// LDS [2 buf][A|B][256*64] = 128 KB, chunk-XOR swizzled (R10-verified).
__global__ __launch_bounds__(512, 2) void gemm256(
    const unsigned short* __restrict__ A, int lda,
    const unsigned short* __restrict__ Bt, int ldb,
    float* __restrict__ C, int Kz) {
  __shared__ __align__(16) unsigned short lds[2][2][256 * 64];

  const int tid = threadIdx.x;
  const int wid = tid >> 6, lane = tid & 63;

  // XCD-aware swizzle (nwg=256 % 8 == 0, bijective)
  const int cpx = gridDim.x >> 3;
  const int wg = ((int)blockIdx.x & 7) * cpx + ((int)blockIdx.x >> 3);
  const int mtile = wg & 15;
  const int ntile = (wg >> 4) & 3;
  const int z = wg >> 6;
  const int brow = mtile * 256, bcol = ntile * 256;
  const int kbase = z * Kz;
  const int NT = Kz >> 6;

  // staging: 32 wave-chunks (1KB) per operand tile; wave w owns chunks {w+8c}.
  // lane l: LDS row (l>>3), dest chunk l&7; global col chunk pre-swizzled
  // (involution: slot(row,ch) holds global chunk ch^(row&7); row&7 == l>>3).
  const int srow = wid * 8 + (lane >> 3);               // + c*64
  const int scol = ((lane & 7) ^ (lane >> 3)) * 8;
  const unsigned short* aS = A + (size_t)(brow + srow) * lda + kbase + scol;
  const unsigned short* bS = Bt + (size_t)(bcol + srow) * ldb + kbase + scol;
  const int lOff = wid * 512;                           // elems; + c*4096; wave-uniform

  const int wm = wid >> 2, wn = wid & 3;                // wave -> 128x64 output block
  const int fr = lane & 15, fg = lane >> 4;
  const int cp0 = ((fg) ^ (fr & 7)) * 8;                // ks=0 un-swizzled chunk
  const int cp1 = ((4 + fg) ^ (fr & 7)) * 8;            // ks=1

  f32x4 acc[8][4] = {};

#define STAGE(t_, buf_)                                                        \
  {                                                                            \
    const unsigned short* a_ = aS + (t_) * 64;                                 \
    const unsigned short* b_ = bS + (t_) * 64;                                 \
    _Pragma("unroll") for (int cc = 0; cc < 4; ++cc) {                         \
      gload_lds16(a_ + (size_t)(cc * 64) * lda, &lds[buf_][0][lOff + cc * 4096]); \
      gload_lds16(b_ + (size_t)(cc * 64) * ldb, &lds[buf_][1][lOff + cc * 4096]); \
    }                                                                          \
  }

  // prologue: tiles 0,1 -> bufs 0,1 (16 loads in flight)
  STAGE(0, 0);
  STAGE(1, 1);

  for (int t = 0; t < NT; ++t) {
    const int c = t & 1;
    // landing gate: retire tile t's 8 loads (oldest); keep tile t+1 in flight
    if (t == NT - 1) { VMCNT0(); } else { VMCNT8(); }
    __builtin_amdgcn_s_barrier();   // all waves' tile-t loads landed

    // read all 24 fragments of tile t
    bf16x8 af[8][2], bfr[4][2];
#pragma unroll
    for (int m = 0; m < 8; ++m) {
      int row = wm * 128 + m * 16 + fr;
      af[m][0] = __builtin_bit_cast(bf16x8,
          *reinterpret_cast<const short8*>(&lds[c][0][row * 64 + cp0]));
      af[m][1] = __builtin_bit_cast(bf16x8,
          *reinterpret_cast<const short8*>(&lds[c][0][row * 64 + cp1]));
    }
#pragma unroll
    for (int n = 0; n < 4; ++n) {
      int row = wn * 64 + n * 16 + fr;
      bfr[n][0] = __builtin_bit_cast(bf16x8,
          *reinterpret_cast<const short8*>(&lds[c][1][row * 64 + cp0]));
      bfr[n][1] = __builtin_bit_cast(bf16x8,
          *reinterpret_cast<const short8*>(&lds[c][1][row * 64 + cp1]));
    }
    LGKM0();
    __builtin_amdgcn_s_barrier();   // buf c globally dead -> safe to restage

    if (t + 2 < NT) STAGE(t + 2, c);  // 8 loads, fly across next ~2 iters

    __builtin_amdgcn_s_setprio(1);
#pragma unroll
    for (int m = 0; m < 8; ++m)
#pragma unroll
      for (int n = 0; n < 4; ++n) {
        f32x4 tmp = __builtin_amdgcn_mfma_f32_16x16x32_bf16(af[m][0], bfr[n][0], acc[m][n], 0, 0, 0);
        acc[m][n] = __builtin_amdgcn_mfma_f32_16x16x32_bf16(af[m][1], bfr[n][1], tmp, 0, 0, 0);
      }
    __builtin_amdgcn_s_setprio(0);
  }
#undef STAGE

  // atomic epilogue; C/D layout (m89-verified): col = lane&15, row = (lane>>4)*4 + j
  const int r0 = brow + wm * 128 + (lane >> 4) * 4;
  const int c0 = bcol + wn * 64 + (lane & 15);
#pragma unroll
  for (int m = 0; m < 8; ++m)
#pragma unroll
    for (int n = 0; n < 4; ++n)
#pragma unroll
      for (int j = 0; j < 4; ++j) {
        size_t idx = (size_t)(r0 + m * 16 + j) * 1024 + (c0 + n * 16);
        atomicAdd(&C[idx], acc[m][n][j]);
      }
}

// ---------------- launcher ----------------

extern "C" void kernel_launch(void* const* d_in, const int* in_sizes, int n_in,
                              void* d_out, int out_size, void* d_ws, size_t ws_size,
                              hipStream_t stream) {
  (void)in_sizes; (void)n_in; (void)out_size;
  const float* x = (const float*)d_in[0];
  const float* Wb = (const float*)d_in[1];
  const float* Ws = (const float*)d_in[2];
  // d_in[3] = mu, folded analytically (mu_g = -2 + g*(4/19))
  float* out = (float*)d_out;
  char* ws = (char*)d_ws;

  // npass so buffers fit ws; pass 0 augmented with base path (K0 = 1024+CI*20)
  int npass = 16;
  for (int np = 2; np <= 16; np <<= 1) {
    size_t K0 = 1024 + (1024 / np) * 20;
    size_t need = 4096ull * K0 * 2 + 1024ull * K0 * 2;
    if (need <= ws_size) { npass = np; break; }
  }
  const int CI = 1024 / npass;
  const int K0 = 1024 + CI * 20;   // pass-0 K (augmented); Kz=K0/4 (2816 @npass=2)
  const int Ksp = CI * 20;         // pass >=1 K; Kz=2560 @npass=2
  unsigned short* A2  = (unsigned short*)ws;
  unsigned short* W2t = (unsigned short*)(ws + 4096ull * K0 * 2);

  hipMemsetAsync(out, 0, 4096ull * 1024 * 4, stream);

  for (int p = 0; p < npass; ++p) {
    const int Kfull = (p == 0) ? K0 : Ksp;
    const int col_off = (p == 0) ? 1024 : 0;
    if (p == 0) {
      prep_silu<<<2048, 256, 0, stream>>>(x, A2, Kfull);
      prep_wt<<<256, 256, 0, stream>>>(Wb, W2t, 1024, Kfull, 0);
    }
    prep_basis<<<4096 * Ksp / 8 / 256, 256, 0, stream>>>(x, A2, p * CI, Ksp, Kfull, col_off);
    prep_wt<<<(Ksp / 64) * 16, 256, 0, stream>>>(Ws + (size_t)p * Ksp * 1024, W2t, Ksp, Kfull, col_off);
    gemm256<<<256, 512, 0, stream>>>(A2, Kfull, W2t, Kfull, out, Kfull / 4);
  }
}